// Round 9
// baseline (219.122 us; speedup 1.0000x reference)
//
#include <hip/hip_runtime.h>
#include <hip/hip_bf16.h>

// MoE MLP (top-2 of 8 experts), T=4096 tokens, D=1024, W=1024.
// R9: GEMM tiles 64x64 (was 128x64), BK=64, double-buffered LDS with ONE
//     barrier per K-iter. LDS 32KB/block -> 5 blocks/CU; 2048 active blocks
//     -> ~20 waves/CU (R6: ~9 avg). Prefetch is in flight for a full compute
//     phase before the barrier drain needs it.
// Retained from R6: XCD map (expert=bid&7), swizzle q^(r&7), ballot
// build_lists, fused transpose+router pre-phase, CAP=1536, combine pass.
// R7 (in-loop fp32 B staging) and R8 (dbuf at 48KB LDS) both regressed; this
// keeps dbuf but inside a 32KB envelope with 2x the block count.

#define T_TOKENS 4096
#define DD 1024
#define EE 8
#define WW 1024
#define CAP 1536          // per-expert capacity (expected ~1024, sigma ~28)
#define BM 64
#define BN 64
#define BK 64
#define MT (CAP / BM)     // 24 m-tiles max per expert
#define NT 16             // 1024/64 n-tiles
#define ABUF (BM * BK)    // shorts per A buffer (8 KB)
#define BBUF (BN * BK)    // shorts per B buffer (8 KB)

typedef short bf16x8 __attribute__((ext_vector_type(8)));
typedef float f32x4 __attribute__((ext_vector_type(4)));

__device__ __forceinline__ void gload_lds16(const void* g, void* l) {
  __builtin_amdgcn_global_load_lds((__attribute__((address_space(1))) void*)(g),
                                   (__attribute__((address_space(3))) void*)(l),
                                   16, 0, 0);
}

__device__ __forceinline__ float bf2f(unsigned short u) {
  union { unsigned int i; float f; } v; v.i = (unsigned int)u << 16; return v.f;
}

// ---------------- fused pre-phase: weight transposes + router ----------------
// blocks [0,2048): w1 transpose; [2048,4096): w2 transpose; [4096,5120): router.
#define TR_BLOCKS 4096
__global__ __launch_bounds__(256) void pre_kernel(
    const float* __restrict__ w1, const float* __restrict__ w2,
    const float* __restrict__ x, const float* __restrict__ rw,
    __hip_bfloat16* __restrict__ w1t, __hip_bfloat16* __restrict__ w2t,
    __hip_bfloat16* __restrict__ xb, int* __restrict__ sel,
    float* __restrict__ wpair)
{
  __shared__ float tile[64][65];
  int b = blockIdx.x;
  if (b < TR_BLOCKS) {
    // ---- transpose part: dst[r*dst_ld+c] = bf16(src[c*src_ld+r]), 64x64 tile ----
    int bx = b & 15;            // dst col tile (16 tiles of 64 over 1024)
    int by = b >> 4;            // 0..255
    const float* src; __hip_bfloat16* dst;
    long src_ld, dst_ld, c0, r0;
    if (by < 128) {
      // w1 [D=1024, E*W=8192] -> w1t [8192, 1024]
      src = w1; dst = w1t; src_ld = EE * WW; dst_ld = DD;
      c0 = (long)bx * 64;       // dst col = src row, 0..1023
      r0 = (long)by * 64;       // dst row = src col, 0..8191
    } else {
      // w2 [E*W, D] expert slice e: [W=1024, D=1024] -> w2t[e] [D=1024, W=1024]
      int z = by - 128;         // 0..127
      int e = z >> 4;           // expert 0..7
      int yy = z & 15;          // dst row tile within expert, 0..15
      src = w2 + (long)e * WW * DD;
      dst = w2t + (long)e * DD * WW;
      src_ld = DD; dst_ld = WW;
      c0 = (long)bx * 64;       // dst col = src row (W dim)
      r0 = (long)yy * 64;       // dst row = src col (D dim)
    }
    int tx = threadIdx.x & 15, ty = threadIdx.x >> 4;
#pragma unroll
    for (int i = 0; i < 4; i++) {
      int sr = ty + 16 * i;
      f32x4 v = *(const f32x4*)(src + (c0 + sr) * src_ld + r0 + tx * 4);
      tile[sr][tx * 4 + 0] = v[0];
      tile[sr][tx * 4 + 1] = v[1];
      tile[sr][tx * 4 + 2] = v[2];
      tile[sr][tx * 4 + 3] = v[3];
    }
    __syncthreads();
#pragma unroll
    for (int i = 0; i < 4; i++) {
      int dr = ty + 16 * i;
      union { __hip_bfloat16 hb[4]; ushort4 u4; } pk;
#pragma unroll
      for (int j = 0; j < 4; j++)
        pk.hb[j] = __float2bfloat16(tile[tx * 4 + j][dr]);
      *(ushort4*)((unsigned short*)dst + (r0 + dr) * dst_ld + c0 + tx * 4) = pk.u4;
    }
  } else {
    // ---- router part: one wave per token, fp32 logits, top-2, no atomics ----
    int lane = threadIdx.x & 63;
    int wave = threadIdx.x >> 6;
    int t = (b - TR_BLOCKS) * 4 + wave;
    const float* xrow = x + (size_t)t * DD;
    float acc[EE];
#pragma unroll
    for (int e = 0; e < EE; e++) acc[e] = 0.f;
#pragma unroll
    for (int i = 0; i < DD / 64; i++) {
      int d = lane + i * 64;
      float xv = xrow[d];
      xb[t * DD + d] = __float2bfloat16(xv);   // fused x -> bf16
#pragma unroll
      for (int e = 0; e < EE; e++) acc[e] += xv * rw[e * DD + d];
    }
#pragma unroll
    for (int e = 0; e < EE; e++) {
#pragma unroll
      for (int off = 32; off > 0; off >>= 1)
        acc[e] += __shfl_down(acc[e], off, 64);
    }
    if (lane == 0) {
      float p[EE];
#pragma unroll
      for (int e = 0; e < EE; e++) p[e] = 1.f / (1.f + expf(-acc[e]));
      // top-2, ties -> lowest index (matches jax.lax.top_k stable ordering)
      int e0 = 0; float b0 = p[0];
      for (int e = 1; e < EE; e++) if (p[e] > b0) { b0 = p[e]; e0 = e; }
      int e1 = -1; float b1 = -1.f;
      for (int e = 0; e < EE; e++) {
        if (e == e0) continue;
        if (p[e] > b1) { b1 = p[e]; e1 = e; }
      }
      float s = b0 + b1 + 1e-20f;
      sel[t] = e0 | (e1 << 8);
      wpair[2 * t]     = b0 / s;
      wpair[2 * t + 1] = b1 / s;
    }
  }
}

// ---------------- build per-expert token lists (1 block, wave-ballot agg) ----------------
__global__ __launch_bounds__(1024) void build_lists(
    const int* __restrict__ sel, int* __restrict__ counts,
    int* __restrict__ idx, int* __restrict__ tslot)
{
  __shared__ int lcnt[EE];
  int tid = threadIdx.x, lane = tid & 63;
  if (tid < EE) lcnt[tid] = 0;
  __syncthreads();
  unsigned long long lower = (1ull << lane) - 1;
#pragma unroll
  for (int j = 0; j < T_TOKENS / 1024; j++) {
    int t = j * 1024 + tid;
    int s = sel[t];
    int e0 = s & 0xff, e1 = (s >> 8) & 0xff;
    int slot0 = 0, slot1 = 0;
#pragma unroll
    for (int e = 0; e < EE; e++) {
      unsigned long long m0 = __ballot(e0 == e);
      unsigned long long m1 = __ballot(e1 == e);
      int c0 = __popcll(m0), c1 = __popcll(m1);
      int base = 0;
      if (lane == 0 && (c0 + c1) > 0) base = atomicAdd(&lcnt[e], c0 + c1);
      base = __shfl(base, 0, 64);
      if (e0 == e) slot0 = base + __popcll(m0 & lower);
      if (e1 == e) slot1 = base + c0 + __popcll(m1 & lower);
    }
    int p0 = e0 * CAP + slot0, p1 = e1 * CAP + slot1;
    idx[p0] = t; idx[p1] = t;
    tslot[2 * t] = p0; tslot[2 * t + 1] = p1;
  }
  __syncthreads();
  if (tid < EE) counts[tid] = lcnt[tid];
}

// ---------------- grouped GEMM1: h = gather(xb) @ W1_e, act = relu(h)^2 ----------------
// 64x64 tile, 4 waves (2x2), dbuf LDS, one barrier per iter. expert = bid&7.
__global__ __launch_bounds__(256) void gemm1_kernel(
    const __hip_bfloat16* __restrict__ xb, const __hip_bfloat16* __restrict__ w1t,
    const int* __restrict__ counts, const int* __restrict__ idx,
    __hip_bfloat16* __restrict__ act)
{
  __shared__ short As[2 * ABUF];  // 16 KB
  __shared__ short Bs[2 * BBUF];  // 16 KB
  int bid = blockIdx.x;
  int e = bid & 7;
  int i = bid >> 3;               // 0..MT*NT-1, nt fastest
  int mt = i >> 4, nt = i & 15;
  int n_e = counts[e];
  if (mt * BM >= n_e) return;

  int tid = threadIdx.x;
  int lane = tid & 63;
  int wave = __builtin_amdgcn_readfirstlane(tid >> 6);
  int wm = (wave >> 1) * 32, wn = (wave & 1) * 32;
  int m16 = lane & 15, qd = lane >> 4;

  // staging: granule = 16B (8 bf16); 8 granule-cols/row; slot s -> row s>>3,
  // swizzled col (s&7)^(row&7). A: 2 issues/thread, B: 2.
  const __hip_bfloat16* gA[2];
  const __hip_bfloat16* gB[2];
#pragma unroll
  for (int i2 = 0; i2 < 2; i2++) {
    int s = i2 * 256 + tid;
    int r = s >> 3;
    int q = (s & 7) ^ (r & 7);                // logical k-granule
    int rowA = mt * BM + r;
    int slot = rowA < n_e ? rowA : n_e - 1;   // clamp tail rows to valid slot
    int tok = idx[e * CAP + slot];
    gA[i2] = xb + (size_t)tok * DD + q * 8;
  }
#pragma unroll
  for (int i2 = 0; i2 < 2; i2++) {
    int s = i2 * 256 + tid;
    int r = s >> 3;
    int q = (s & 7) ^ (r & 7);
    gB[i2] = w1t + ((size_t)e * WW + nt * BN + r) * DD + q * 8;
  }
  short* stA[2];
  short* stB[2];
#pragma unroll
  for (int i2 = 0; i2 < 2; i2++) stA[i2] = As + (i2 * 256 + wave * 64) * 8;
#pragma unroll
  for (int i2 = 0; i2 < 2; i2++) stB[i2] = Bs + (i2 * 256 + wave * 64) * 8;

  int aoff[2][2], boff[2][2];
#pragma unroll
  for (int i2 = 0; i2 < 2; i2++) {
    int r = wm + i2 * 16 + m16;
#pragma unroll
    for (int h = 0; h < 2; h++)
      aoff[i2][h] = (r * 8 + ((qd + h * 4) ^ (r & 7))) * 8;
  }
#pragma unroll
  for (int j = 0; j < 2; j++) {
    int r = wn + j * 16 + m16;
#pragma unroll
    for (int h = 0; h < 2; h++)
      boff[j][h] = (r * 8 + ((qd + h * 4) ^ (r & 7))) * 8;
  }

  f32x4 zero = {0.f, 0.f, 0.f, 0.f};
  f32x4 acc[2][2];
#pragma unroll
  for (int mi = 0; mi < 2; mi++)
#pragma unroll
    for (int ni = 0; ni < 2; ni++) acc[mi][ni] = zero;

  // prologue: stage k0=0 into buffer 0
#pragma unroll
  for (int i2 = 0; i2 < 2; i2++) gload_lds16(gA[i2], stA[i2]);
#pragma unroll
  for (int i2 = 0; i2 < 2; i2++) gload_lds16(gB[i2], stB[i2]);
  __syncthreads();

  int p = 0;
  for (int k0 = 0; k0 < DD; k0 += BK) {
    int np = p ^ 1;
    if (k0 + BK < DD) {   // prefetch next tile into the other buffer
      gload_lds16(gA[0] + k0 + BK, stA[0] + np * ABUF);
      gload_lds16(gA[1] + k0 + BK, stA[1] + np * ABUF);
      gload_lds16(gB[0] + k0 + BK, stB[0] + np * BBUF);
      gload_lds16(gB[1] + k0 + BK, stB[1] + np * BBUF);
    }
    const short* Ab = As + p * ABUF;
    const short* Bb = Bs + p * BBUF;
#pragma unroll
    for (int h = 0; h < 2; h++) {
      bf16x8 af[2], bfr[2];
#pragma unroll
      for (int i2 = 0; i2 < 2; i2++) af[i2] = *(const bf16x8*)(Ab + aoff[i2][h]);
#pragma unroll
      for (int j = 0; j < 2; j++) bfr[j] = *(const bf16x8*)(Bb + boff[j][h]);
#pragma unroll
      for (int mi = 0; mi < 2; mi++)
#pragma unroll
        for (int ni = 0; ni < 2; ni++)
          acc[mi][ni] = __builtin_amdgcn_mfma_f32_16x16x32_bf16(
              af[mi], bfr[ni], acc[mi][ni], 0, 0, 0);
    }
    __syncthreads();   // one barrier/iter: drains prefetch + guards buffer reuse
    p = np;
  }

  // epilogue: relu^2 -> bf16 act[(e*CAP + slot)][col]
#pragma unroll
  for (int mi = 0; mi < 2; mi++) {
#pragma unroll
    for (int reg = 0; reg < 4; reg++) {
      int rowt = mt * BM + wm + mi * 16 + qd * 4 + reg;
      if (rowt < n_e) {
#pragma unroll
        for (int ni = 0; ni < 2; ni++) {
          float v = acc[mi][ni][reg];
          v = v > 0.f ? v * v : 0.f;
          int col = nt * BN + wn + ni * 16 + m16;
          act[((size_t)e * CAP + rowt) * WW + col] = __float2bfloat16(v);
        }
      }
    }
  }
}

// ---------------- grouped GEMM2: y = act @ W2_e (raw bf16 y, no atomics) ----------------
__global__ __launch_bounds__(256) void gemm2_kernel(
    const __hip_bfloat16* __restrict__ act, const __hip_bfloat16* __restrict__ w2t,
    const int* __restrict__ counts, __hip_bfloat16* __restrict__ y)
{
  __shared__ short As[2 * ABUF];
  __shared__ short Bs[2 * BBUF];
  int bid = blockIdx.x;
  int e = bid & 7;
  int i = bid >> 3;
  int mt = i >> 4, nt = i & 15;
  int n_e = counts[e];
  if (mt * BM >= n_e) return;

  int tid = threadIdx.x;
  int lane = tid & 63;
  int wave = __builtin_amdgcn_readfirstlane(tid >> 6);
  int wm = (wave >> 1) * 32, wn = (wave & 1) * 32;
  int m16 = lane & 15, qd = lane >> 4;

  const __hip_bfloat16* gA[2];
  const __hip_bfloat16* gB[2];
#pragma unroll
  for (int i2 = 0; i2 < 2; i2++) {
    int s = i2 * 256 + tid;
    int r = s >> 3;
    int q = (s & 7) ^ (r & 7);
    gA[i2] = act + ((size_t)e * CAP + mt * BM + r) * WW + q * 8;  // rows >= n_e: garbage, row-isolated
  }
#pragma unroll
  for (int i2 = 0; i2 < 2; i2++) {
    int s = i2 * 256 + tid;
    int r = s >> 3;
    int q = (s & 7) ^ (r & 7);
    gB[i2] = w2t + ((size_t)e * DD + nt * BN + r) * WW + q * 8;
  }
  short* stA[2];
  short* stB[2];
#pragma unroll
  for (int i2 = 0; i2 < 2; i2++) stA[i2] = As + (i2 * 256 + wave * 64) * 8;
#pragma unroll
  for (int i2 = 0; i2 < 2; i2++) stB[i2] = Bs + (i2 * 256 + wave * 64) * 8;

  int aoff[2][2], boff[2][2];
#pragma unroll
  for (int i2 = 0; i2 < 2; i2++) {
    int r = wm + i2 * 16 + m16;
#pragma unroll
    for (int h = 0; h < 2; h++)
      aoff[i2][h] = (r * 8 + ((qd + h * 4) ^ (r & 7))) * 8;
  }
#pragma unroll
  for (int j = 0; j < 2; j++) {
    int r = wn + j * 16 + m16;
#pragma unroll
    for (int h = 0; h < 2; h++)
      boff[j][h] = (r * 8 + ((qd + h * 4) ^ (r & 7))) * 8;
  }

  f32x4 zero = {0.f, 0.f, 0.f, 0.f};
  f32x4 acc[2][2];
#pragma unroll
  for (int mi = 0; mi < 2; mi++)
#pragma unroll
    for (int ni = 0; ni < 2; ni++) acc[mi][ni] = zero;

#pragma unroll
  for (int i2 = 0; i2 < 2; i2++) gload_lds16(gA[i2], stA[i2]);
#pragma unroll
  for (int i2 = 0; i2 < 2; i2++) gload_lds16(gB[i2], stB[i2]);
  __syncthreads();

  int p = 0;
  for (int k0 = 0; k0 < WW; k0 += BK) {
    int np = p ^ 1;
    if (k0 + BK < WW) {
      gload_lds16(gA[0] + k0 + BK, stA[0] + np * ABUF);
      gload_lds16(gA[1] + k0 + BK, stA[1] + np * ABUF);
      gload_lds16(gB[0] + k0 + BK, stB[0] + np * BBUF);
      gload_lds16(gB[1] + k0 + BK, stB[1] + np * BBUF);
    }
    const short* Ab = As + p * ABUF;
    const short* Bb = Bs + p * BBUF;
#pragma unroll
    for (int h = 0; h < 2; h++) {
      bf16x8 af[2], bfr[2];
#pragma unroll
      for (int i2 = 0; i2 < 2; i2++) af[i2] = *(const bf16x8*)(Ab + aoff[i2][h]);
#pragma unroll
      for (int j = 0; j < 2; j++) bfr[j] = *(const bf16x8*)(Bb + boff[j][h]);
#pragma unroll
      for (int mi = 0; mi < 2; mi++)
#pragma unroll
        for (int ni = 0; ni < 2; ni++)
          acc[mi][ni] = __builtin_amdgcn_mfma_f32_16x16x32_bf16(
              af[mi], bfr[ni], acc[mi][ni], 0, 0, 0);
    }
    __syncthreads();
    p = np;
  }

  // epilogue: raw y (weights applied in combine)
#pragma unroll
  for (int mi = 0; mi < 2; mi++) {
#pragma unroll
    for (int reg = 0; reg < 4; reg++) {
      int slot = mt * BM + wm + mi * 16 + qd * 4 + reg;
      if (slot < n_e) {
#pragma unroll
        for (int ni = 0; ni < 2; ni++) {
          int col = nt * BN + wn + ni * 16 + m16;
          y[((size_t)e * CAP + slot) * DD + col] = __float2bfloat16(acc[mi][ni][reg]);
        }
      }
    }
  }
}

// ---------------- combine: out[t] = w0*y[slot0] + w1*y[slot1] ----------------
__global__ __launch_bounds__(256) void combine_kernel(
    const __hip_bfloat16* __restrict__ y, const int* __restrict__ tslot,
    const float* __restrict__ wpair, float* __restrict__ out)
{
  int t = blockIdx.x;
  int c = threadIdx.x * 4;
  int s0 = tslot[2 * t], s1 = tslot[2 * t + 1];
  float w0 = wpair[2 * t], w1 = wpair[2 * t + 1];
  const unsigned short* yu = (const unsigned short*)y;
  ushort4 a = *(const ushort4*)(yu + (size_t)s0 * DD + c);
  ushort4 bq = *(const ushort4*)(yu + (size_t)s1 * DD + c);
  f32x4 o;
  o[0] = w0 * bf2f(a.x) + w1 * bf2f(bq.x);
  o[1] = w0 * bf2f(a.y) + w1 * bf2f(bq.y);
  o[2] = w0 * bf2f(a.z) + w1 * bf2f(bq.z);
  o[3] = w0 * bf2f(a.w) + w1 * bf2f(bq.w);
  *(f32x4*)(out + (size_t)t * DD + c) = o;
}

extern "C" void kernel_launch(void* const* d_in, const int* in_sizes, int n_in,
                              void* d_out, int out_size, void* d_ws, size_t ws_size,
                              hipStream_t stream)
{
  const float* x  = (const float*)d_in[0];
  const float* rw = (const float*)d_in[1];
  const float* w1 = (const float*)d_in[2];
  const float* w2 = (const float*)d_in[3];
  float* out = (float*)d_out;

  char* ws = (char*)d_ws;
  __hip_bfloat16* xb  = (__hip_bfloat16*)ws;  ws += (size_t)T_TOKENS * DD * 2;
  __hip_bfloat16* w1t = (__hip_bfloat16*)ws;  ws += (size_t)EE * WW * DD * 2;
  __hip_bfloat16* w2t = (__hip_bfloat16*)ws;  ws += (size_t)EE * DD * WW * 2;
  __hip_bfloat16* act = (__hip_bfloat16*)ws;  ws += (size_t)EE * CAP * WW * 2;
  __hip_bfloat16* y   = (__hip_bfloat16*)ws;  ws += (size_t)EE * CAP * DD * 2;
  int*   counts = (int*)ws;                   ws += 256;
  int*   idx    = (int*)ws;                   ws += (size_t)EE * CAP * 4;
  int*   sel    = (int*)ws;                   ws += (size_t)T_TOKENS * 4;
  int*   tslot  = (int*)ws;                   ws += (size_t)T_TOKENS * 8;
  float* wpair  = (float*)ws;                 ws += (size_t)T_TOKENS * 8;

  // pre: blocks [0,2048) w1 transpose, [2048,4096) w2 transpose, [4096,5120) router
  pre_kernel<<<TR_BLOCKS + T_TOKENS / 4, 256, 0, stream>>>(
      w1, w2, x, rw, w1t, w2t, xb, sel, wpair);
  build_lists<<<1, 1024, 0, stream>>>(sel, counts, idx, tslot);
  gemm1_kernel<<<EE * MT * NT, 256, 0, stream>>>(xb, w1t, counts, idx, act);
  gemm2_kernel<<<EE * MT * NT, 256, 0, stream>>>(act, w2t, counts, y);
  combine_kernel<<<T_TOKENS, 256, 0, stream>>>(y, tslot, wpair, out);
}

// Round 10
// 194.762 us; speedup vs baseline: 1.1251x; 1.1251x over previous
//
#include <hip/hip_runtime.h>
#include <hip/hip_bf16.h>

// MoE MLP (top-2 of 8 experts), T=4096 tokens, D=1024, W=1024.
// R10: R6 GEMM structure restored exactly (128x64, BK=64, single-buffer —
//      R7/R8/R9 K-loop variants all regressed). New: w2 transpose blocks are
//      FUSED INTO THE GEMM1 LAUNCH (blocks >= 1536), backfilling idle CU slack
//      of the latency-bound gemm1 instead of serializing in the pre phase.
// Pipeline: [pre: w1T + router] -> [build_lists ballot] ->
//           [gemm1 + w2T fused] -> [gemm2] -> [combine]

#define T_TOKENS 4096
#define DD 1024
#define EE 8
#define WW 1024
#define CAP 1536          // per-expert capacity (expected ~1024, sigma ~28)
#define BM 128
#define BN 64
#define BK 64
#define MT (CAP / BM)     // 12 m-tiles max per expert
#define NT 16             // 1024/64 n-tiles
#define G1_BLOCKS (EE * MT * NT)   // 1536 gemm1 blocks (div by 8 -> XCD map intact)
#define W2T_BLOCKS 2048            // 8 experts x 16 x 16 tiles of 64x64

typedef short bf16x8 __attribute__((ext_vector_type(8)));
typedef float f32x4 __attribute__((ext_vector_type(4)));

__device__ __forceinline__ void gload_lds16(const void* g, void* l) {
  __builtin_amdgcn_global_load_lds((__attribute__((address_space(1))) void*)(g),
                                   (__attribute__((address_space(3))) void*)(l),
                                   16, 0, 0);
}

__device__ __forceinline__ float bf2f(unsigned short u) {
  union { unsigned int i; float f; } v; v.i = (unsigned int)u << 16; return v.f;
}

// ---------------- pre-phase: w1 transpose + router ----------------
// blocks [0,2048): w1 transpose; [2048,3072): router.
#define TR1_BLOCKS 2048
__global__ __launch_bounds__(256) void pre_kernel(
    const float* __restrict__ w1, const float* __restrict__ x,
    const float* __restrict__ rw, __hip_bfloat16* __restrict__ w1t,
    __hip_bfloat16* __restrict__ xb, int* __restrict__ sel,
    float* __restrict__ wpair)
{
  __shared__ float tile[64][65];
  int b = blockIdx.x;
  if (b < TR1_BLOCKS) {
    // w1 [D=1024, E*W=8192] -> w1t [8192, 1024]; 64x64 tile
    int bx = b & 15;            // dst col tile
    int by = b >> 4;            // 0..127 dst row tile
    long c0 = (long)bx * 64;    // dst col = src row
    long r0 = (long)by * 64;    // dst row = src col
    int tx = threadIdx.x & 15, ty = threadIdx.x >> 4;
#pragma unroll
    for (int i = 0; i < 4; i++) {
      int sr = ty + 16 * i;
      f32x4 v = *(const f32x4*)(w1 + (c0 + sr) * (EE * WW) + r0 + tx * 4);
      tile[sr][tx * 4 + 0] = v[0];
      tile[sr][tx * 4 + 1] = v[1];
      tile[sr][tx * 4 + 2] = v[2];
      tile[sr][tx * 4 + 3] = v[3];
    }
    __syncthreads();
#pragma unroll
    for (int i = 0; i < 4; i++) {
      int dr = ty + 16 * i;
      union { __hip_bfloat16 hb[4]; ushort4 u4; } pk;
#pragma unroll
      for (int j = 0; j < 4; j++)
        pk.hb[j] = __float2bfloat16(tile[tx * 4 + j][dr]);
      *(ushort4*)((unsigned short*)w1t + (r0 + dr) * DD + c0 + tx * 4) = pk.u4;
    }
  } else {
    // router: one wave per token, fp32 logits, top-2, no atomics
    int lane = threadIdx.x & 63;
    int wave = threadIdx.x >> 6;
    int t = (b - TR1_BLOCKS) * 4 + wave;
    const float* xrow = x + (size_t)t * DD;
    float acc[EE];
#pragma unroll
    for (int e = 0; e < EE; e++) acc[e] = 0.f;
#pragma unroll
    for (int i = 0; i < DD / 64; i++) {
      int d = lane + i * 64;
      float xv = xrow[d];
      xb[t * DD + d] = __float2bfloat16(xv);   // fused x -> bf16
#pragma unroll
      for (int e = 0; e < EE; e++) acc[e] += xv * rw[e * DD + d];
    }
#pragma unroll
    for (int e = 0; e < EE; e++) {
#pragma unroll
      for (int off = 32; off > 0; off >>= 1)
        acc[e] += __shfl_down(acc[e], off, 64);
    }
    if (lane == 0) {
      float p[EE];
#pragma unroll
      for (int e = 0; e < EE; e++) p[e] = 1.f / (1.f + expf(-acc[e]));
      // top-2, ties -> lowest index (matches jax.lax.top_k stable ordering)
      int e0 = 0; float b0 = p[0];
      for (int e = 1; e < EE; e++) if (p[e] > b0) { b0 = p[e]; e0 = e; }
      int e1 = -1; float b1 = -1.f;
      for (int e = 0; e < EE; e++) {
        if (e == e0) continue;
        if (p[e] > b1) { b1 = p[e]; e1 = e; }
      }
      float s = b0 + b1 + 1e-20f;
      sel[t] = e0 | (e1 << 8);
      wpair[2 * t]     = b0 / s;
      wpair[2 * t + 1] = b1 / s;
    }
  }
}

// ---------------- build per-expert token lists (1 block, wave-ballot agg) ----------------
__global__ __launch_bounds__(1024) void build_lists(
    const int* __restrict__ sel, int* __restrict__ counts,
    int* __restrict__ idx, int* __restrict__ tslot)
{
  __shared__ int lcnt[EE];
  int tid = threadIdx.x, lane = tid & 63;
  if (tid < EE) lcnt[tid] = 0;
  __syncthreads();
  unsigned long long lower = (1ull << lane) - 1;
#pragma unroll
  for (int j = 0; j < T_TOKENS / 1024; j++) {
    int t = j * 1024 + tid;
    int s = sel[t];
    int e0 = s & 0xff, e1 = (s >> 8) & 0xff;
    int slot0 = 0, slot1 = 0;
#pragma unroll
    for (int e = 0; e < EE; e++) {
      unsigned long long m0 = __ballot(e0 == e);
      unsigned long long m1 = __ballot(e1 == e);
      int c0 = __popcll(m0), c1 = __popcll(m1);
      int base = 0;
      if (lane == 0 && (c0 + c1) > 0) base = atomicAdd(&lcnt[e], c0 + c1);
      base = __shfl(base, 0, 64);
      if (e0 == e) slot0 = base + __popcll(m0 & lower);
      if (e1 == e) slot1 = base + c0 + __popcll(m1 & lower);
    }
    int p0 = e0 * CAP + slot0, p1 = e1 * CAP + slot1;
    idx[p0] = t; idx[p1] = t;
    tslot[2 * t] = p0; tslot[2 * t + 1] = p1;
  }
  __syncthreads();
  if (tid < EE) counts[tid] = lcnt[tid];
}

// ---------------- gemm1 (R6 structure) + fused w2 transpose ----------------
// blocks [0,1536): gemm1, expert = bid&7 (XCD map). blocks [1536,3584): w2T.
__global__ __launch_bounds__(256) void gemm1_fused(
    const __hip_bfloat16* __restrict__ xb, const __hip_bfloat16* __restrict__ w1t,
    const int* __restrict__ counts, const int* __restrict__ idx,
    __hip_bfloat16* __restrict__ act,
    const float* __restrict__ w2, __hip_bfloat16* __restrict__ w2t)
{
  __shared__ short smem[BM * BK + BN * BK];   // 24 KB (gemm) / 16.6 KB (transpose tile)
  int bid = blockIdx.x;
  int tid = threadIdx.x;

  if (bid >= G1_BLOCKS) {
    // ---- w2 transpose: [E*W, D] slice e [W,D] -> w2t[e] [D, W] ----
    int tb = bid - G1_BLOCKS;   // 0..2047
    int bx = tb & 15;           // dst col tile
    int z = tb >> 4;            // 0..127
    int e = z >> 4, yy = z & 15;
    const float* src = w2 + (long)e * WW * DD;
    __hip_bfloat16* dst = w2t + (long)e * DD * WW;
    long c0 = (long)bx * 64;    // dst col = src row (W dim)
    long r0 = (long)yy * 64;    // dst row = src col (D dim)
    float (*tile)[65] = (float(*)[65])smem;
    int tx = tid & 15, ty = tid >> 4;
#pragma unroll
    for (int i = 0; i < 4; i++) {
      int sr = ty + 16 * i;
      f32x4 v = *(const f32x4*)(src + (c0 + sr) * DD + r0 + tx * 4);
      tile[sr][tx * 4 + 0] = v[0];
      tile[sr][tx * 4 + 1] = v[1];
      tile[sr][tx * 4 + 2] = v[2];
      tile[sr][tx * 4 + 3] = v[3];
    }
    __syncthreads();
#pragma unroll
    for (int i = 0; i < 4; i++) {
      int dr = ty + 16 * i;
      union { __hip_bfloat16 hb[4]; ushort4 u4; } pk;
#pragma unroll
      for (int j = 0; j < 4; j++)
        pk.hb[j] = __float2bfloat16(tile[tx * 4 + j][dr]);
      *(ushort4*)((unsigned short*)dst + (r0 + dr) * WW + c0 + tx * 4) = pk.u4;
    }
    return;
  }

  // ---- gemm1: h = gather(xb) @ W1_e, act = relu(h)^2 (exact R6 structure) ----
  short* As = smem;             // BM*BK shorts = 16 KB
  short* Bs = smem + BM * BK;   // BN*BK shorts = 8 KB
  int e = bid & 7;
  int i = bid >> 3;             // nt fastest
  int mt = i >> 4, nt = i & 15;
  int n_e = counts[e];
  if (mt * BM >= n_e) return;

  int lane = tid & 63;
  int wave = __builtin_amdgcn_readfirstlane(tid >> 6);
  int wm = (wave >> 1) * 64, wn = (wave & 1) * 32;
  int m16 = lane & 15, qd = lane >> 4;

  // staging: granule = 16B (8 bf16); 8 granule-cols/row; slot s -> row s>>3,
  // swizzled col (s&7)^(row&7). A: 4 issues/thread, B: 2.
  const __hip_bfloat16* gA[4];
  const __hip_bfloat16* gB[2];
#pragma unroll
  for (int i2 = 0; i2 < 4; i2++) {
    int s = i2 * 256 + tid;
    int r = s >> 3;
    int q = (s & 7) ^ (r & 7);                // logical k-granule
    int rowA = mt * BM + r;
    int slot = rowA < n_e ? rowA : n_e - 1;   // clamp tail rows to valid slot
    int tok = idx[e * CAP + slot];
    gA[i2] = xb + (size_t)tok * DD + q * 8;
  }
#pragma unroll
  for (int i2 = 0; i2 < 2; i2++) {
    int s = i2 * 256 + tid;
    int r = s >> 3;
    int q = (s & 7) ^ (r & 7);
    gB[i2] = w1t + ((size_t)e * WW + nt * BN + r) * DD + q * 8;
  }
  short* stA[4];
  short* stB[2];
#pragma unroll
  for (int i2 = 0; i2 < 4; i2++) stA[i2] = As + (i2 * 256 + wave * 64) * 8;
#pragma unroll
  for (int i2 = 0; i2 < 2; i2++) stB[i2] = Bs + (i2 * 256 + wave * 64) * 8;

  int aoff[4][2], boff[2][2];
#pragma unroll
  for (int i2 = 0; i2 < 4; i2++) {
    int r = wm + i2 * 16 + m16;
#pragma unroll
    for (int h = 0; h < 2; h++)
      aoff[i2][h] = (r * 8 + ((qd + h * 4) ^ (r & 7))) * 8;
  }
#pragma unroll
  for (int j = 0; j < 2; j++) {
    int r = wn + j * 16 + m16;
#pragma unroll
    for (int h = 0; h < 2; h++)
      boff[j][h] = (r * 8 + ((qd + h * 4) ^ (r & 7))) * 8;
  }

  f32x4 zero = {0.f, 0.f, 0.f, 0.f};
  f32x4 acc[4][2];
#pragma unroll
  for (int mi = 0; mi < 4; mi++)
#pragma unroll
    for (int ni = 0; ni < 2; ni++) acc[mi][ni] = zero;

  for (int k0 = 0; k0 < DD; k0 += BK) {
    gload_lds16(gA[0] + k0, stA[0]);
    gload_lds16(gA[1] + k0, stA[1]);
    gload_lds16(gA[2] + k0, stA[2]);
    gload_lds16(gA[3] + k0, stA[3]);
    gload_lds16(gB[0] + k0, stB[0]);
    gload_lds16(gB[1] + k0, stB[1]);
    __syncthreads();
#pragma unroll
    for (int h = 0; h < 2; h++) {
      bf16x8 af[4], bfr[2];
#pragma unroll
      for (int i2 = 0; i2 < 4; i2++) af[i2] = *(const bf16x8*)(As + aoff[i2][h]);
#pragma unroll
      for (int j = 0; j < 2; j++) bfr[j] = *(const bf16x8*)(Bs + boff[j][h]);
#pragma unroll
      for (int mi = 0; mi < 4; mi++)
#pragma unroll
        for (int ni = 0; ni < 2; ni++)
          acc[mi][ni] = __builtin_amdgcn_mfma_f32_16x16x32_bf16(
              af[mi], bfr[ni], acc[mi][ni], 0, 0, 0);
    }
    __syncthreads();
  }

  // epilogue: relu^2 -> bf16 act[(e*CAP + slot)][col]
#pragma unroll
  for (int mi = 0; mi < 4; mi++) {
#pragma unroll
    for (int reg = 0; reg < 4; reg++) {
      int rowt = mt * BM + wm + mi * 16 + qd * 4 + reg;
      if (rowt < n_e) {
#pragma unroll
        for (int ni = 0; ni < 2; ni++) {
          float v = acc[mi][ni][reg];
          v = v > 0.f ? v * v : 0.f;
          int col = nt * BN + wn + ni * 16 + m16;
          act[((size_t)e * CAP + rowt) * WW + col] = __float2bfloat16(v);
        }
      }
    }
  }
}

// ---------------- grouped GEMM2: y = act @ W2_e (raw bf16 y, R6 structure) ----------------
__global__ __launch_bounds__(256) void gemm2_kernel(
    const __hip_bfloat16* __restrict__ act, const __hip_bfloat16* __restrict__ w2t,
    const int* __restrict__ counts, __hip_bfloat16* __restrict__ y)
{
  __shared__ short As[BM * BK];
  __shared__ short Bs[BN * BK];
  int bid = blockIdx.x;
  int e = bid & 7;
  int i = bid >> 3;
  int mt = i >> 4, nt = i & 15;
  int n_e = counts[e];
  if (mt * BM >= n_e) return;

  int tid = threadIdx.x;
  int lane = tid & 63;
  int wave = __builtin_amdgcn_readfirstlane(tid >> 6);
  int wm = (wave >> 1) * 64, wn = (wave & 1) * 32;
  int m16 = lane & 15, qd = lane >> 4;

  const __hip_bfloat16* gA[4];
  const __hip_bfloat16* gB[2];
#pragma unroll
  for (int i2 = 0; i2 < 4; i2++) {
    int s = i2 * 256 + tid;
    int r = s >> 3;
    int q = (s & 7) ^ (r & 7);
    gA[i2] = act + ((size_t)e * CAP + mt * BM + r) * WW + q * 8;  // rows >= n_e: garbage, row-isolated
  }
#pragma unroll
  for (int i2 = 0; i2 < 2; i2++) {
    int s = i2 * 256 + tid;
    int r = s >> 3;
    int q = (s & 7) ^ (r & 7);
    gB[i2] = w2t + ((size_t)e * DD + nt * BN + r) * WW + q * 8;
  }
  short* stA[4];
  short* stB[2];
#pragma unroll
  for (int i2 = 0; i2 < 4; i2++) stA[i2] = As + (i2 * 256 + wave * 64) * 8;
#pragma unroll
  for (int i2 = 0; i2 < 2; i2++) stB[i2] = Bs + (i2 * 256 + wave * 64) * 8;

  int aoff[4][2], boff[2][2];
#pragma unroll
  for (int i2 = 0; i2 < 4; i2++) {
    int r = wm + i2 * 16 + m16;
#pragma unroll
    for (int h = 0; h < 2; h++)
      aoff[i2][h] = (r * 8 + ((qd + h * 4) ^ (r & 7))) * 8;
  }
#pragma unroll
  for (int j = 0; j < 2; j++) {
    int r = wn + j * 16 + m16;
#pragma unroll
    for (int h = 0; h < 2; h++)
      boff[j][h] = (r * 8 + ((qd + h * 4) ^ (r & 7))) * 8;
  }

  f32x4 zero = {0.f, 0.f, 0.f, 0.f};
  f32x4 acc[4][2];
#pragma unroll
  for (int mi = 0; mi < 4; mi++)
#pragma unroll
    for (int ni = 0; ni < 2; ni++) acc[mi][ni] = zero;

  for (int k0 = 0; k0 < WW; k0 += BK) {
    gload_lds16(gA[0] + k0, stA[0]);
    gload_lds16(gA[1] + k0, stA[1]);
    gload_lds16(gA[2] + k0, stA[2]);
    gload_lds16(gA[3] + k0, stA[3]);
    gload_lds16(gB[0] + k0, stB[0]);
    gload_lds16(gB[1] + k0, stB[1]);
    __syncthreads();
#pragma unroll
    for (int h = 0; h < 2; h++) {
      bf16x8 af[4], bfr[2];
#pragma unroll
      for (int i2 = 0; i2 < 4; i2++) af[i2] = *(const bf16x8*)(As + aoff[i2][h]);
#pragma unroll
      for (int j = 0; j < 2; j++) bfr[j] = *(const bf16x8*)(Bs + boff[j][h]);
#pragma unroll
      for (int mi = 0; mi < 4; mi++)
#pragma unroll
        for (int ni = 0; ni < 2; ni++)
          acc[mi][ni] = __builtin_amdgcn_mfma_f32_16x16x32_bf16(
              af[mi], bfr[ni], acc[mi][ni], 0, 0, 0);
    }
    __syncthreads();
  }

  // epilogue: raw y (weights applied in combine)
#pragma unroll
  for (int mi = 0; mi < 4; mi++) {
#pragma unroll
    for (int reg = 0; reg < 4; reg++) {
      int slot = mt * BM + wm + mi * 16 + qd * 4 + reg;
      if (slot < n_e) {
#pragma unroll
        for (int ni = 0; ni < 2; ni++) {
          int col = nt * BN + wn + ni * 16 + m16;
          y[((size_t)e * CAP + slot) * DD + col] = __float2bfloat16(acc[mi][ni][reg]);
        }
      }
    }
  }
}

// ---------------- combine: out[t] = w0*y[slot0] + w1*y[slot1] ----------------
__global__ __launch_bounds__(256) void combine_kernel(
    const __hip_bfloat16* __restrict__ y, const int* __restrict__ tslot,
    const float* __restrict__ wpair, float* __restrict__ out)
{
  int t = blockIdx.x;
  int c = threadIdx.x * 4;
  int s0 = tslot[2 * t], s1 = tslot[2 * t + 1];
  float w0 = wpair[2 * t], w1 = wpair[2 * t + 1];
  const unsigned short* yu = (const unsigned short*)y;
  ushort4 a = *(const ushort4*)(yu + (size_t)s0 * DD + c);
  ushort4 bq = *(const ushort4*)(yu + (size_t)s1 * DD + c);
  f32x4 o;
  o[0] = w0 * bf2f(a.x) + w1 * bf2f(bq.x);
  o[1] = w0 * bf2f(a.y) + w1 * bf2f(bq.y);
  o[2] = w0 * bf2f(a.z) + w1 * bf2f(bq.z);
  o[3] = w0 * bf2f(a.w) + w1 * bf2f(bq.w);
  *(f32x4*)(out + (size_t)t * DD + c) = o;
}

extern "C" void kernel_launch(void* const* d_in, const int* in_sizes, int n_in,
                              void* d_out, int out_size, void* d_ws, size_t ws_size,
                              hipStream_t stream)
{
  const float* x  = (const float*)d_in[0];
  const float* rw = (const float*)d_in[1];
  const float* w1 = (const float*)d_in[2];
  const float* w2 = (const float*)d_in[3];
  float* out = (float*)d_out;

  char* ws = (char*)d_ws;
  __hip_bfloat16* xb  = (__hip_bfloat16*)ws;  ws += (size_t)T_TOKENS * DD * 2;
  __hip_bfloat16* w1t = (__hip_bfloat16*)ws;  ws += (size_t)EE * WW * DD * 2;
  __hip_bfloat16* w2t = (__hip_bfloat16*)ws;  ws += (size_t)EE * DD * WW * 2;
  __hip_bfloat16* act = (__hip_bfloat16*)ws;  ws += (size_t)EE * CAP * WW * 2;
  __hip_bfloat16* y   = (__hip_bfloat16*)ws;  ws += (size_t)EE * CAP * DD * 2;
  int*   counts = (int*)ws;                   ws += 256;
  int*   idx    = (int*)ws;                   ws += (size_t)EE * CAP * 4;
  int*   sel    = (int*)ws;                   ws += (size_t)T_TOKENS * 4;
  int*   tslot  = (int*)ws;                   ws += (size_t)T_TOKENS * 8;
  float* wpair  = (float*)ws;                 ws += (size_t)T_TOKENS * 8;

  // pre: blocks [0,2048) w1 transpose, [2048,3072) router
  pre_kernel<<<TR1_BLOCKS + T_TOKENS / 4, 256, 0, stream>>>(
      w1, x, rw, w1t, xb, sel, wpair);
  build_lists<<<1, 1024, 0, stream>>>(sel, counts, idx, tslot);
  // gemm1 (1536 blocks, XCD-mapped) + w2 transpose (2048 blocks) in one launch
  gemm1_fused<<<G1_BLOCKS + W2T_BLOCKS, 256, 0, stream>>>(
      xb, w1t, counts, idx, act, w2, w2t);
  gemm2_kernel<<<EE * MT * NT, 256, 0, stream>>>(act, w2t, counts, y);
  combine_kernel<<<T_TOKENS, 256, 0, stream>>>(y, tslot, wpair, out);
}